// Round 3
// baseline (879.374 us; speedup 1.0000x reference)
//
#include <hip/hip_runtime.h>

#define NODES_PER_BLOCK 64

__global__ void zero_i_kernel(int* __restrict__ p, int total) {
  int i = blockIdx.x * blockDim.x + threadIdx.x;
  if (i < total) p[i] = 0;
}

// cnt[col[e]]++  (int atomics)
__global__ void hist_kernel(const int* __restrict__ col, int* __restrict__ cnt, int e) {
  int i = blockIdx.x * blockDim.x + threadIdx.x;
  if (i < e) atomicAdd(cnt + col[i], 1);
}

// dinv[v] = rsqrt(cnt[v] + 1)   (+1 = self loop)
__global__ void dinv_kernel(const int* __restrict__ cnt, float* __restrict__ dinv, int n) {
  int i = blockIdx.x * blockDim.x + threadIdx.x;
  if (i < n) dinv[i] = rsqrtf((float)cnt[i] + 1.0f);
}

// exclusive scan of cnt -> start[0..n]; cnt_cursor overwritten with prefix (cursor init)
__global__ __launch_bounds__(1024) void scan_kernel(int* __restrict__ cnt_cursor,
                                                    int* __restrict__ start, int n) {
  __shared__ int lds[1024];
  int t = threadIdx.x;
  int chunk = (n + 1023) >> 10;
  int b0 = t * chunk;
  int b1 = min(b0 + chunk, n);
  int sum = 0;
  for (int i = b0; i < b1; i++) sum += cnt_cursor[i];
  lds[t] = sum;
  __syncthreads();
  for (int off = 1; off < 1024; off <<= 1) {
    int v = (t >= off) ? lds[t - off] : 0;
    __syncthreads();
    lds[t] += v;
    __syncthreads();
  }
  int p = lds[t] - sum;  // exclusive prefix
  for (int i = b0; i < b1; i++) {
    int c = cnt_cursor[i];
    start[i] = p;
    cnt_cursor[i] = p;   // cursor for fill
    p += c;
  }
  if (t == 1023) start[n] = lds[1023];
}

// csr_src[cursor[col[e]]++] = row[e]
__global__ void fill_kernel(const int* __restrict__ row, const int* __restrict__ col,
                            int* __restrict__ cursor, int* __restrict__ csr, int e) {
  int i = blockIdx.x * blockDim.x + threadIdx.x;
  if (i < e) {
    int c = col[i];
    int pos = atomicAdd(cursor + c, 1);
    csr[pos] = row[i];
  }
}

// s1 = (x @ W1) * dinv ; x [n,128] f32, W1 [128,16]
__global__ __launch_bounds__(256) void mm1_kernel(const float* __restrict__ x,
                                                  const float* __restrict__ W1,
                                                  const float* __restrict__ dinv,
                                                  float* __restrict__ s1, int n) {
  __shared__ float xs[NODES_PER_BLOCK][129];
  __shared__ float ws[128 * 16];
  int t = threadIdx.x;
  for (int i = t; i < 128 * 16; i += 256) ws[i] = W1[i];
  int base = blockIdx.x * NODES_PER_BLOCK;
  for (int i = t * 4; i < NODES_PER_BLOCK * 128; i += 256 * 4) {
    int nn = i >> 7, k = i & 127;
    if (base + nn < n) {
      float4 v = *(const float4*)(x + (size_t)(base + nn) * 128 + k);
      xs[nn][k] = v.x; xs[nn][k + 1] = v.y; xs[nn][k + 2] = v.z; xs[nn][k + 3] = v.w;
    }
  }
  __syncthreads();
  int nn = t >> 2;
  int j0 = (t & 3) * 4;
  float a0 = 0, a1 = 0, a2 = 0, a3 = 0;
  #pragma unroll 8
  for (int k = 0; k < 128; k++) {
    float xv = xs[nn][k];
    const float* wr = ws + k * 16 + j0;
    a0 += xv * wr[0]; a1 += xv * wr[1]; a2 += xv * wr[2]; a3 += xv * wr[3];
  }
  int node = base + nn;
  if (node < n) {
    float d = dinv[node];
    float4 o; o.x = a0 * d; o.y = a1 * d; o.z = a2 * d; o.w = a3 * d;
    *(float4*)(s1 + (size_t)node * 16 + j0) = o;
  }
}

// layer-1 gather + fused post-op: s2 = relu(dinv*(self + sum_in) + b1) * dinv
__global__ __launch_bounds__(256) void gather1_kernel(const int* __restrict__ start,
                                                      const int* __restrict__ csr,
                                                      const float* __restrict__ s1,
                                                      const float* __restrict__ dinv,
                                                      const float* __restrict__ b1,
                                                      float* __restrict__ s2, int n) {
  int t = threadIdx.x;
  int node = blockIdx.x * 16 + (t >> 4);
  int f = t & 15;
  if (node >= n) return;
  float a = s1[(size_t)node * 16 + f];   // self loop
  int e0 = start[node], e1 = start[node + 1];
  int ee = e0;
  for (; ee + 1 < e1; ee += 2) {
    int u0 = csr[ee], u1 = csr[ee + 1];
    float v0 = s1[(size_t)u0 * 16 + f];
    float v1 = s1[(size_t)u1 * 16 + f];
    a += v0; a += v1;
  }
  if (ee < e1) a += s1[(size_t)csr[ee] * 16 + f];
  float d = dinv[node];
  float h = fmaxf(fmaf(d, a, b1[f]), 0.0f);
  s2[(size_t)node * 16 + f] = h * d;
}

// layer-2 gather: acc = dinv*(self + sum_in)   (pre-scaled for the W2 transform)
__global__ __launch_bounds__(256) void gather2_kernel(const int* __restrict__ start,
                                                      const int* __restrict__ csr,
                                                      const float* __restrict__ s2,
                                                      const float* __restrict__ dinv,
                                                      float* __restrict__ acc, int n) {
  int t = threadIdx.x;
  int node = blockIdx.x * 16 + (t >> 4);
  int f = t & 15;
  if (node >= n) return;
  float a = s2[(size_t)node * 16 + f];
  int e0 = start[node], e1 = start[node + 1];
  int ee = e0;
  for (; ee + 1 < e1; ee += 2) {
    int u0 = csr[ee], u1 = csr[ee + 1];
    float v0 = s2[(size_t)u0 * 16 + f];
    float v1 = s2[(size_t)u1 * 16 + f];
    a += v0; a += v1;
  }
  if (ee < e1) a += s2[(size_t)csr[ee] * 16 + f];
  acc[(size_t)node * 16 + f] = dinv[node] * a;
}

// out[v][j] = sum_k acc[v][k] * W2[k][j] + b2[j]
__global__ __launch_bounds__(256) void final_kernel(const float* __restrict__ acc,
                                                    const float* __restrict__ W2,
                                                    const float* __restrict__ b2,
                                                    float* __restrict__ out, int n) {
  __shared__ float w2s[16 * 64];
  __shared__ float b2s[64];
  int t = threadIdx.x;
  for (int i = t; i < 16 * 64; i += 256) w2s[i] = W2[i];
  if (t < 64) b2s[t] = b2[t];
  __syncthreads();
  int node = blockIdx.x * 4 + (t >> 6);
  int j = t & 63;
  if (node < n) {
    const float* ap = acc + (size_t)node * 16;
    float o = b2s[j];
    #pragma unroll
    for (int k = 0; k < 16; k++) o = fmaf(ap[k], w2s[k * 64 + j], o);
    out[(size_t)node * 64 + j] = o;
  }
}

extern "C" void kernel_launch(void* const* d_in, const int* in_sizes, int n_in,
                              void* d_out, int out_size, void* d_ws, size_t ws_size,
                              hipStream_t stream) {
  const float* x = (const float*)d_in[0];
  const int* ei = (const int*)d_in[1];   // int32 (JAX x64 disabled)
  const float* W1 = (const float*)d_in[2];
  const float* b1 = (const float*)d_in[3];
  const float* W2 = (const float*)d_in[4];
  const float* b2 = (const float*)d_in[5];
  float* out = (float*)d_out;

  int n = in_sizes[0] / 128;   // 100000
  int e = in_sizes[1] / 2;     // 3200000
  const int* row = ei;         // sources
  const int* col = ei + e;     // targets (aggregation index)

  // workspace layout (4B elements; regions padded to 4-elem multiples for float4 stores)
  int* istart = (int*)d_ws;                       // n+1 (alloc n+4)
  int* icursor = istart + (n + 4);                // n
  int* csr = icursor + n;                         // e
  float* dinv = (float*)(csr + e);                // n
  float* s1 = dinv + n;                           // 16n (reused as acc for layer 2)
  float* s2 = s1 + (size_t)n * 16;                // 16n
  float* acc = s1;                                // layer-1 feats dead by then

  // ---- CSR build (once; shared by both layers) ----
  zero_i_kernel<<<(n + 255) / 256, 256, 0, stream>>>(icursor, n);
  hist_kernel<<<(e + 255) / 256, 256, 0, stream>>>(col, icursor, e);
  dinv_kernel<<<(n + 255) / 256, 256, 0, stream>>>(icursor, dinv, n);
  scan_kernel<<<1, 1024, 0, stream>>>(icursor, istart, n);
  fill_kernel<<<(e + 255) / 256, 256, 0, stream>>>(row, col, icursor, csr, e);

  // ---- layer 1: transform (128->16) then gather-aggregate ----
  mm1_kernel<<<(n + NODES_PER_BLOCK - 1) / NODES_PER_BLOCK, 256, 0, stream>>>(x, W1, dinv, s1, n);
  gather1_kernel<<<(n + 15) / 16, 256, 0, stream>>>(istart, csr, s1, dinv, b1, s2, n);

  // ---- layer 2: gather-aggregate (16-wide) then transform (16->64) ----
  gather2_kernel<<<(n + 15) / 16, 256, 0, stream>>>(istart, csr, s2, dinv, acc, n);
  final_kernel<<<(n + 3) / 4, 256, 0, stream>>>(acc, W2, b2, out, n);
}